// Round 6
// baseline (2224.590 us; speedup 1.0000x reference)
//
#include <hip/hip_runtime.h>
#include <hip/hip_bf16.h>

typedef __bf16 bf16x8 __attribute__((ext_vector_type(8)));
typedef __bf16 bf16x4 __attribute__((ext_vector_type(4)));
typedef float  f32x4  __attribute__((ext_vector_type(4)));
typedef float  f32x16 __attribute__((ext_vector_type(16)));
typedef int    i32x4  __attribute__((ext_vector_type(4)));

// Problem dims
#define NB 64
#define NT 512
#define ND 512
#define NH 1024
#define NG 4096  // 4H

// workspace layout (bytes)
// h triple buffer: buf0 @ OFF_H, buf1 @ +128K, buf2 @ +256K
// buf2 ALIASES the first 128KB of Ebf — Ebf dead after k_gemm_xw; buf2's
// tag-init fill launches after the GEMM.
#define OFF_H   4096u       // 3 x 64 x 1024 bf16 = 3 x 128 KB
#define OFF_EB  266240u     // E as bf16: 32000x512 (32 MB)
#define OFF_WT  33034240u   // W^T bf16: 4096x512
#define OFF_UT  37228544u   // U^T bf16: 4096x1024
#define OFF_XW  45617152u   // xw bf16: (T,B,4096) = 256 MB

#define HBUF_STRIDE 131072u // one h buffer: 64*1024*2

__device__ __forceinline__ void gl_lds16(const void* g, void* l) {
  typedef const unsigned __attribute__((address_space(1)))* gp_t;
  typedef unsigned __attribute__((address_space(3)))* lp_t;
  __builtin_amdgcn_global_load_lds((gp_t)g, (lp_t)l, 16, 0, 0);
}

__device__ __forceinline__ float sigf(float x) {
  return 1.0f / (1.0f + __expf(-x));
}

// 8 coherent (LLC) 16B loads from consecutive 64B offsets + drain.
// Outputs EARLY-CLOBBER: must not alias the address pair.
__device__ __forceinline__ void load_h_frags(unsigned long long a, i32x4* A) {
  asm volatile(
      "global_load_dwordx4 %0, %[a], off sc0 sc1\n\t"
      "global_load_dwordx4 %1, %[a], off offset:64 sc0 sc1\n\t"
      "global_load_dwordx4 %2, %[a], off offset:128 sc0 sc1\n\t"
      "global_load_dwordx4 %3, %[a], off offset:192 sc0 sc1\n\t"
      "global_load_dwordx4 %4, %[a], off offset:256 sc0 sc1\n\t"
      "global_load_dwordx4 %5, %[a], off offset:320 sc0 sc1\n\t"
      "global_load_dwordx4 %6, %[a], off offset:384 sc0 sc1\n\t"
      "global_load_dwordx4 %7, %[a], off offset:448 sc0 sc1\n\t"
      "s_waitcnt vmcnt(0)"
      : "=&v"(A[0]), "=&v"(A[1]), "=&v"(A[2]), "=&v"(A[3]),
        "=&v"(A[4]), "=&v"(A[5]), "=&v"(A[6]), "=&v"(A[7])
      : [a] "v"(a)
      : "memory");
}

// ---------------- prep kernels ----------------
__global__ void k_zero(uint4* p, int n) {
  int i = blockIdx.x * blockDim.x + threadIdx.x;
  int stride = gridDim.x * blockDim.x;
  uint4 z; z.x = 0; z.y = 0; z.z = 0; z.w = 0;
  for (; i < n; i += stride) p[i] = z;
}

__global__ void k_fill(uint4* p, int n) {
  int i = blockIdx.x * blockDim.x + threadIdx.x;
  int stride = gridDim.x * blockDim.x;
  uint4 s; s.x = 0xFFFFFFFFu; s.y = 0xFFFFFFFFu; s.z = 0xFFFFFFFFu; s.w = 0xFFFFFFFFu;
  for (; i < n; i += stride) p[i] = s;
}

__global__ void k_cvt(const float* __restrict__ in, __bf16* __restrict__ out, int n4) {
  int i = blockIdx.x * blockDim.x + threadIdx.x;
  int stride = gridDim.x * blockDim.x;
  for (; i < n4; i += stride) {
    float4 f = ((const float4*)in)[i];
    bf16x4 o;
    o.x = (__bf16)f.x; o.y = (__bf16)f.y; o.z = (__bf16)f.z; o.w = (__bf16)f.w;
    ((bf16x4*)out)[i] = o;
  }
}

// out[c][r] = (bf16) in[r][c];  in is (R,C) f32, out is (C,R) bf16
__global__ void k_transpose(const float* __restrict__ in, __bf16* __restrict__ out,
                            int R, int C) {
  __shared__ __bf16 tile[64][72];
  int c0 = blockIdx.x * 64, r0 = blockIdx.y * 64;
  for (int i = threadIdx.x; i < 4096; i += 256) {
    int r = i >> 6, c = i & 63;
    tile[r][c] = (__bf16)in[(size_t)(r0 + r) * C + c0 + c];
  }
  __syncthreads();
  for (int i = threadIdx.x; i < 4096; i += 256) {
    int c = i >> 6, r = i & 63;
    out[(size_t)(c0 + c) * R + r0 + r] = tile[r][c];
  }
}

// ---------------- GEMM1: xw[t][b][g] = E[ids[bt]] @ W + b ----------------
__global__ __launch_bounds__(256, 2) void k_gemm_xw(
    const int* __restrict__ ids, const __bf16* __restrict__ Ebf,
    const __bf16* __restrict__ Wt, const float* __restrict__ bias,
    __bf16* __restrict__ xw) {
  __shared__ __align__(16) char smem[32768];  // A tile 16K + B tile 16K
  char* ldsA = smem;
  char* ldsB = smem + 16384;

  const int tid = threadIdx.x;
  const int lane = tid & 63, w = tid >> 6;
  const int bm = blockIdx.x >> 5;          // 0..255
  const int bn0 = (blockIdx.x & 31) * 128; // col base

  const int l8r = lane >> 3, pc = lane & 7;
  size_t asrc[4], bsrc[4];
#pragma unroll
  for (int is = 0; is < 4; ++is) {
    int row = w * 32 + is * 8 + l8r;
    int id = ids[bm * 128 + row];
    asrc[is] = (size_t)id * ND + (size_t)(((pc ^ (row & 7)) * 8));
    int gn = bn0 + row;
    bsrc[is] = (size_t)gn * ND + (size_t)(((pc ^ (row & 7)) * 8));
  }

  const int rm = (w & 1) * 64, cn = (w >> 1) * 64;
  const int l31 = lane & 31, l5 = lane >> 5;
  f32x16 acc[2][2] = {};

  for (int kk = 0; kk < 8; ++kk) {
#pragma unroll
    for (int is = 0; is < 4; ++is) {
      gl_lds16(Ebf + asrc[is] + kk * 64, ldsA + w * 4096 + is * 1024);
      gl_lds16(Wt + bsrc[is] + kk * 64, ldsB + w * 4096 + is * 1024);
    }
    __syncthreads();
#pragma unroll
    for (int ksub = 0; ksub < 4; ++ksub) {
      int c = ksub * 2 + l5;
      bf16x8 af[2], bfr[2];
#pragma unroll
      for (int mt = 0; mt < 2; ++mt) {
        int row = rm + mt * 32 + l31;
        af[mt] = *(const bf16x8*)(ldsA + row * 128 + ((c ^ (row & 7)) << 4));
      }
#pragma unroll
      for (int nt = 0; nt < 2; ++nt) {
        int rowb = cn + nt * 32 + l31;
        bfr[nt] = *(const bf16x8*)(ldsB + rowb * 128 + ((c ^ (rowb & 7)) << 4));
      }
#pragma unroll
      for (int mt = 0; mt < 2; ++mt)
#pragma unroll
        for (int nt = 0; nt < 2; ++nt)
          acc[mt][nt] = __builtin_amdgcn_mfma_f32_32x32x16_bf16(
              af[mt], bfr[nt], acc[mt][nt], 0, 0, 0);
    }
    __syncthreads();
  }

#pragma unroll
  for (int nt = 0; nt < 2; ++nt) {
    int g = bn0 + cn + nt * 32 + l31;
    float bv = bias[g];
#pragma unroll
    for (int mt = 0; mt < 2; ++mt) {
#pragma unroll
      for (int r = 0; r < 16; ++r) {
        int row = (r & 3) + 8 * (r >> 2) + 4 * l5;
        int bt = bm * 128 + rm + mt * 32 + row;
        int tt = bt & 511, bb = bt >> 9;
        xw[(size_t)(tt * 64 + bb) * NG + g] = (__bf16)(acc[mt][nt][r] + bv);
      }
    }
  }
}

// ---------------- persistent LSTM scan ----------------
// 256 blocks x 256 thr. block: ms=bid&3 -> batches [ms*16,+16); nj=bid>>2 -> j in [nj*16,+16)
// wave w K-splits [w*256,+256). U fragments REGISTER-RESIDENT.
//
// Sync protocol (tag-in-data): h = o*sig(c) >= 0 so the bf16 sign bit is free.
// Producer stores h_{t+1} with sign bit = (t+1)&1. Consumer polls buf[t%3]
// until EVERY element's sign bit == t&1. Stale occupant (h_{t-3}) has the
// opposite parity — can never look ready; partially-landed stores fail the
// per-element check (2B stores are atomic) and simply retry.
// FUSED POLL: the full 8-fragment load is itself the readiness check (tags
// travel with the data) — one LLC trip in the ready case, no separate probe.
// Overwrite safety (no end-of-step barrier needed): seeing h_t complete
// implies every group block released h_t, which implies it finished its
// step-(t-1) loads, hence its step-(t-2) loads long before — so writing
// h_{t+1} over h_{t-2}'s slot is safe. zp is double-buffered by step parity
// (the one remaining __syncthreads separates zp write from zp reduce).
// ost staging is per-thread-private — needs no barrier at all.
__global__ __launch_bounds__(256, 1) void k_lstm(
    const int* __restrict__ ids, const __bf16* __restrict__ xw,
    const __bf16* __restrict__ Ut, float* __restrict__ out,
    __bf16* __restrict__ hb) {
  extern __shared__ char dynlds[];
  float* ost = (float*)dynlds;               // 32 KB: U staging window, then out stage [32][256]
  float* zp  = (float*)(dynlds + 32768);     // 2 x 32 KB: parity-double-buffered z partials

  const int tid = threadIdx.x;
  const int lane = tid & 63, w = tid >> 6;
  const int bid = blockIdx.x;
  const int ms = bid & 3, nj = bid >> 2;
  const int b0 = ms * 16, j0 = nj * 16;

  const int bn = lane & 15;  // n (j-local) for B frags / MFMA
  const int kc = lane >> 4;  // k-chunk 0..3

  // ---- stage U fragments through a 32KB window, chunk per gate q ----
  bf16x8 Bf[8][4];
#pragma unroll
  for (int q = 0; q < 4; ++q) {
#pragma unroll
    for (int ks = 0; ks < 8; ++ks) {
      const __bf16* src =
          Ut + (size_t)(q * NH + j0 + bn) * NH + w * 256 + ks * 32 + kc * 8;
      gl_lds16(src, (char*)dynlds + ((w * 8 + ks) << 10));
    }
    __syncthreads();
#pragma unroll
    for (int ks = 0; ks < 8; ++ks)
      Bf[ks][q] =
          *(const bf16x8*)((char*)dynlds + (((w * 8 + ks) << 6) + lane) * 16);
    __syncthreads();
  }

  const int eb = tid >> 4, ej = tid & 15;
  const int bg = b0 + eb, jg = j0 + ej;
  float c_st = 0.0f, h_st = 0.0f;

  const int am = lane & 15;  // batch row for A frags
  const unsigned long long hlane =
      (unsigned long long)(hb) + ((b0 + am) * NH + w * 256 + kc * 8) * 2ull;
  const unsigned long long hown =
      (unsigned long long)(hb) + (bg * NH + jg) * 2ull;

  unsigned offR = 0, offW = HBUF_STRIDE, offF = 2 * HBUF_STRIDE;

  // conflict-free zp read index: par(b) = ((b>>2)^b)&1 puts the 4 b's a wave
  // touches into both bank halves (2-way on both write and read = free)
  const int parE = ((eb >> 2) ^ eb) & 1;
  const int rbase = eb * 32 + (parE << 4) + ej;

  // pipeline prologue: xw/ids for t=0
  const __bf16* xwp0 = xw + ((size_t)(0 * 64 + bg) << 12) + jg;
  __bf16 xr0 = xwp0[0], xr1 = xwp0[NH], xr2 = xwp0[2 * NH], xr3 = xwp0[3 * NH];
  int idv = ids[bg * NT + 0];

#pragma unroll 1
  for (int t = 0; t < NT; ++t) {
    const unsigned long long hbR = hlane + offR;
    const unsigned expectTag = (t & 1) ? 0x80008000u : 0u;

    // A) FUSED poll: full slice load + tag verify — one LLC trip when ready
    i32x4 Ar[8];
    for (;;) {
      load_h_frags(hbR, Ar);
      unsigned bad = 0;
#pragma unroll
      for (int i = 0; i < 8; ++i)
        bad |= (unsigned)((Ar[i][0] ^ (int)expectTag) | (Ar[i][1] ^ (int)expectTag) |
                          (Ar[i][2] ^ (int)expectTag) | (Ar[i][3] ^ (int)expectTag));
      if (__all((int)((bad & 0x80008000u) == 0))) break;
    }

    // B) prefetch xw/ids for t+1 — plain cached loads (cross-block LLC reuse).
    //    Drained by next step's poll vmcnt(0); residual latency overlaps the spin.
    const int tp = (t + 1) & (NT - 1);
    const __bf16* xwn = xw + ((size_t)(tp * 64 + bg) << 12) + jg;
    __bf16 nx0 = xwn[0], nx1 = xwn[NH], nx2 = xwn[2 * NH], nx3 = xwn[3 * NH];
    int nid = ids[bg * NT + tp];

    // C) strip generation tags (sign bits) — only odd steps carry them
    if (t & 1) {
#pragma unroll
      for (int i = 0; i < 8; ++i) {
        Ar[i][0] &= 0x7FFF7FFF; Ar[i][1] &= 0x7FFF7FFF;
        Ar[i][2] &= 0x7FFF7FFF; Ar[i][3] &= 0x7FFF7FFF;
      }
    }

    // D) MFMA: z partials, B-fragments from registers
    f32x4 acc[4] = {{0, 0, 0, 0}, {0, 0, 0, 0}, {0, 0, 0, 0}, {0, 0, 0, 0}};
#pragma unroll
    for (int ks = 0; ks < 8; ++ks) {
      bf16x8 a = __builtin_bit_cast(bf16x8, Ar[ks]);
#pragma unroll
      for (int q = 0; q < 4; ++q)
        acc[q] = __builtin_amdgcn_mfma_f32_16x16x32_bf16(a, Bf[ks][q], acc[q], 0, 0, 0);
    }

    // E) partials to parity LDS buffer, conflict-free: b = kc*4+r, par = (kc^r)&1
    float* zpp = zp + ((t & 1) << 13);
#pragma unroll
    for (int q = 0; q < 4; ++q)
#pragma unroll
      for (int r = 0; r < 4; ++r)
        zpp[((w * 4 + q) << 9) + ((kc * 4 + r) << 5) + (((kc ^ r) & 1) << 4) + bn] =
            acc[q][r];
    __syncthreads();  // BLOCK GATE: all 4 waves' polls passed + zp complete

    // F) reduce + gates
    float z0 = 0, z1 = 0, z2 = 0, z3 = 0;
#pragma unroll
    for (int wv = 0; wv < 4; ++wv) {
      z0 += zpp[((wv * 4 + 0) << 9) + rbase];
      z1 += zpp[((wv * 4 + 1) << 9) + rbase];
      z2 += zpp[((wv * 4 + 2) << 9) + rbase];
      z3 += zpp[((wv * 4 + 3) << 9) + rbase];
    }
    z0 += (float)xr0; z1 += (float)xr1; z2 += (float)xr2; z3 += (float)xr3;
    float iv = sigf(z0), fv = sigf(z1), gv = sigf(z2), ov = sigf(z3);
    float cn = fv * c_st + iv * gv;
    float hn = ov * sigf(cn);
    bool m = (idv != 0);
    c_st = m ? cn : c_st;
    h_st = m ? hn : h_st;

    // G) release h_{t+1} immediately — tagged with (t+1)&1 in the sign bit.
    {
      unsigned hv = (unsigned)__builtin_bit_cast(unsigned short, (__bf16)h_st) |
                    ((unsigned)((t + 1) & 1) << 15);
      unsigned long long ha = hown + offW;
      asm volatile(
          "global_store_short %[a], %[d], off sc0 sc1"
          :: [a] "v"(ha), [d] "v"(hv) : "memory");
    }

    // H) stage out in LDS (thread-private slots — no barrier needed);
    //    dump every 32 steps (non-temporal, off the serial path)
    ost[(t & 31) * 256 + tid] = h_st;
    if ((t & 31) == 31) {
      float* ob = out + (size_t)bg * (NT * NH) + (size_t)(t - 31) * NH + jg;
#pragma unroll
      for (int s = 0; s < 32; ++s)
        __builtin_nontemporal_store(ost[s * 256 + tid], ob + (size_t)s * NH);
    }

    // I) rotate buffers + pipeline registers (no end-of-step barrier:
    //    zp parity double-buffer makes next step's writes safe)
    unsigned tmp = offR; offR = offW; offW = offF; offF = tmp;
    xr0 = nx0; xr1 = nx1; xr2 = nx2; xr3 = nx3; idv = nid;
  }

  // final h, c
  out[33554432u + bg * NH + jg] = h_st;
  out[33554432u + 65536u + bg * NH + jg] = c_st;
}

// ---------------- launch ----------------
extern "C" void kernel_launch(void* const* d_in, const int* in_sizes, int n_in,
                              void* d_out, int out_size, void* d_ws, size_t ws_size,
                              hipStream_t stream) {
  const int* ids = (const int*)d_in[0];
  const float* E = (const float*)d_in[1];
  const float* W = (const float*)d_in[2];
  const float* U = (const float*)d_in[3];
  const float* bias = (const float*)d_in[4];
  char* ws = (char*)d_ws;
  __bf16* Ebf = (__bf16*)(ws + OFF_EB);
  __bf16* Wt = (__bf16*)(ws + OFF_WT);
  __bf16* Ut = (__bf16*)(ws + OFF_UT);
  __bf16* xw = (__bf16*)(ws + OFF_XW);
  __bf16* hb = (__bf16*)(ws + OFF_H);
  float* out = (float*)d_out;

  // allow 96 KB dynamic LDS for k_lstm (idempotent; safe under graph capture)
  (void)hipFuncSetAttribute((const void*)k_lstm,
                            hipFuncAttributeMaxDynamicSharedMemorySize, 98304);

  // buf0 = h_0 = zeros (tag 0 == ready for t=0); buf1 = zeros (sign clear ==
  // NOT ready for t=1, which expects tag 1)
  hipLaunchKernelGGL(k_zero, dim3(64), dim3(256), 0, stream, (uint4*)(ws + OFF_H), 16384);
  // E -> bf16
  hipLaunchKernelGGL(k_cvt, dim3(2048), dim3(256), 0, stream, E, Ebf, 4096000);
  // W^T, U^T -> bf16
  hipLaunchKernelGGL(k_transpose, dim3(64, 8), dim3(256), 0, stream, W, Wt, 512, 4096);
  hipLaunchKernelGGL(k_transpose, dim3(64, 16), dim3(256), 0, stream, U, Ut, 1024, 4096);
  // xw = gather(E)@W + b
  hipLaunchKernelGGL(k_gemm_xw, dim3(8192), dim3(256), 0, stream, ids, Ebf, Wt, bias, xw);
  // buf2: sign-set fill (NOT ready for t=2, which expects tag 0).
  // Aliases head of Ebf — must run AFTER the GEMM.
  hipLaunchKernelGGL(k_fill, dim3(32), dim3(256), 0, stream,
                     (uint4*)(ws + OFF_H + 2 * HBUF_STRIDE), 8192);
  // persistent LSTM scan
  hipLaunchKernelGGL(k_lstm, dim3(256), dim3(256), 98304, stream, ids, xw, Ut, out, hb);
}

// Round 7
// 1676.112 us; speedup vs baseline: 1.3272x; 1.3272x over previous
//
#include <hip/hip_runtime.h>
#include <hip/hip_bf16.h>

typedef __bf16 bf16x8 __attribute__((ext_vector_type(8)));
typedef __bf16 bf16x4 __attribute__((ext_vector_type(4)));
typedef float  f32x4  __attribute__((ext_vector_type(4)));
typedef float  f32x16 __attribute__((ext_vector_type(16)));
typedef int    i32x4  __attribute__((ext_vector_type(4)));

// Problem dims
#define NB 64
#define NT 512
#define ND 512
#define NH 1024
#define NG 4096  // 4H

// workspace layout (bytes)
// h triple buffer: buf0 @ OFF_H, buf1 @ +128K, buf2 @ +256K
// buf2 ALIASES the first 128KB of Ebf — Ebf dead after k_gemm_xw; buf2's
// tag-init fill launches after the GEMM.
#define OFF_H   4096u       // 3 x 64 x 1024 bf16 = 3 x 128 KB
#define OFF_EB  266240u     // E as bf16: 32000x512 (32 MB)
#define OFF_WT  33034240u   // W^T bf16: 4096x512
#define OFF_UT  37228544u   // U^T bf16: 4096x1024
#define OFF_XW  45617152u   // xw bf16: (T,B,4096) = 256 MB

#define HBUF_STRIDE 131072u // one h buffer: 64*1024*2

__device__ __forceinline__ void gl_lds16(const void* g, void* l) {
  typedef const unsigned __attribute__((address_space(1)))* gp_t;
  typedef unsigned __attribute__((address_space(3)))* lp_t;
  __builtin_amdgcn_global_load_lds((gp_t)g, (lp_t)l, 16, 0, 0);
}

__device__ __forceinline__ float sigf(float x) {
  return 1.0f / (1.0f + __expf(-x));
}

// 8 coherent (LLC) 16B loads from consecutive 64B offsets + drain.
// Outputs EARLY-CLOBBER: must not alias the address pair.
__device__ __forceinline__ void load_h_frags(unsigned long long a, i32x4* A) {
  asm volatile(
      "global_load_dwordx4 %0, %[a], off sc0 sc1\n\t"
      "global_load_dwordx4 %1, %[a], off offset:64 sc0 sc1\n\t"
      "global_load_dwordx4 %2, %[a], off offset:128 sc0 sc1\n\t"
      "global_load_dwordx4 %3, %[a], off offset:192 sc0 sc1\n\t"
      "global_load_dwordx4 %4, %[a], off offset:256 sc0 sc1\n\t"
      "global_load_dwordx4 %5, %[a], off offset:320 sc0 sc1\n\t"
      "global_load_dwordx4 %6, %[a], off offset:384 sc0 sc1\n\t"
      "global_load_dwordx4 %7, %[a], off offset:448 sc0 sc1\n\t"
      "s_waitcnt vmcnt(0)"
      : "=&v"(A[0]), "=&v"(A[1]), "=&v"(A[2]), "=&v"(A[3]),
        "=&v"(A[4]), "=&v"(A[5]), "=&v"(A[6]), "=&v"(A[7])
      : [a] "v"(a)
      : "memory");
}

// ---------------- prep kernels ----------------
__global__ void k_zero(uint4* p, int n) {
  int i = blockIdx.x * blockDim.x + threadIdx.x;
  int stride = gridDim.x * blockDim.x;
  uint4 z; z.x = 0; z.y = 0; z.z = 0; z.w = 0;
  for (; i < n; i += stride) p[i] = z;
}

__global__ void k_fill(uint4* p, int n) {
  int i = blockIdx.x * blockDim.x + threadIdx.x;
  int stride = gridDim.x * blockDim.x;
  uint4 s; s.x = 0xFFFFFFFFu; s.y = 0xFFFFFFFFu; s.z = 0xFFFFFFFFu; s.w = 0xFFFFFFFFu;
  for (; i < n; i += stride) p[i] = s;
}

__global__ void k_cvt(const float* __restrict__ in, __bf16* __restrict__ out, int n4) {
  int i = blockIdx.x * blockDim.x + threadIdx.x;
  int stride = gridDim.x * blockDim.x;
  for (; i < n4; i += stride) {
    float4 f = ((const float4*)in)[i];
    bf16x4 o;
    o.x = (__bf16)f.x; o.y = (__bf16)f.y; o.z = (__bf16)f.z; o.w = (__bf16)f.w;
    ((bf16x4*)out)[i] = o;
  }
}

// out[c][r] = (bf16) in[r][c];  in is (R,C) f32, out is (C,R) bf16
__global__ void k_transpose(const float* __restrict__ in, __bf16* __restrict__ out,
                            int R, int C) {
  __shared__ __bf16 tile[64][72];
  int c0 = blockIdx.x * 64, r0 = blockIdx.y * 64;
  for (int i = threadIdx.x; i < 4096; i += 256) {
    int r = i >> 6, c = i & 63;
    tile[r][c] = (__bf16)in[(size_t)(r0 + r) * C + c0 + c];
  }
  __syncthreads();
  for (int i = threadIdx.x; i < 4096; i += 256) {
    int c = i >> 6, r = i & 63;
    out[(size_t)(c0 + c) * R + r0 + r] = tile[r][c];
  }
}

// ---------------- GEMM1: xw[t][b][g] = E[ids[bt]] @ W + b ----------------
__global__ __launch_bounds__(256, 2) void k_gemm_xw(
    const int* __restrict__ ids, const __bf16* __restrict__ Ebf,
    const __bf16* __restrict__ Wt, const float* __restrict__ bias,
    __bf16* __restrict__ xw) {
  __shared__ __align__(16) char smem[32768];  // A tile 16K + B tile 16K
  char* ldsA = smem;
  char* ldsB = smem + 16384;

  const int tid = threadIdx.x;
  const int lane = tid & 63, w = tid >> 6;
  const int bm = blockIdx.x >> 5;          // 0..255
  const int bn0 = (blockIdx.x & 31) * 128; // col base

  const int l8r = lane >> 3, pc = lane & 7;
  size_t asrc[4], bsrc[4];
#pragma unroll
  for (int is = 0; is < 4; ++is) {
    int row = w * 32 + is * 8 + l8r;
    int id = ids[bm * 128 + row];
    asrc[is] = (size_t)id * ND + (size_t)(((pc ^ (row & 7)) * 8));
    int gn = bn0 + row;
    bsrc[is] = (size_t)gn * ND + (size_t)(((pc ^ (row & 7)) * 8));
  }

  const int rm = (w & 1) * 64, cn = (w >> 1) * 64;
  const int l31 = lane & 31, l5 = lane >> 5;
  f32x16 acc[2][2] = {};

  for (int kk = 0; kk < 8; ++kk) {
#pragma unroll
    for (int is = 0; is < 4; ++is) {
      gl_lds16(Ebf + asrc[is] + kk * 64, ldsA + w * 4096 + is * 1024);
      gl_lds16(Wt + bsrc[is] + kk * 64, ldsB + w * 4096 + is * 1024);
    }
    __syncthreads();
#pragma unroll
    for (int ksub = 0; ksub < 4; ++ksub) {
      int c = ksub * 2 + l5;
      bf16x8 af[2], bfr[2];
#pragma unroll
      for (int mt = 0; mt < 2; ++mt) {
        int row = rm + mt * 32 + l31;
        af[mt] = *(const bf16x8*)(ldsA + row * 128 + ((c ^ (row & 7)) << 4));
      }
#pragma unroll
      for (int nt = 0; nt < 2; ++nt) {
        int rowb = cn + nt * 32 + l31;
        bfr[nt] = *(const bf16x8*)(ldsB + rowb * 128 + ((c ^ (rowb & 7)) << 4));
      }
#pragma unroll
      for (int mt = 0; mt < 2; ++mt)
#pragma unroll
        for (int nt = 0; nt < 2; ++nt)
          acc[mt][nt] = __builtin_amdgcn_mfma_f32_32x32x16_bf16(
              af[mt], bfr[nt], acc[mt][nt], 0, 0, 0);
    }
    __syncthreads();
  }

#pragma unroll
  for (int nt = 0; nt < 2; ++nt) {
    int g = bn0 + cn + nt * 32 + l31;
    float bv = bias[g];
#pragma unroll
    for (int mt = 0; mt < 2; ++mt) {
#pragma unroll
      for (int r = 0; r < 16; ++r) {
        int row = (r & 3) + 8 * (r >> 2) + 4 * l5;
        int bt = bm * 128 + rm + mt * 32 + row;
        int tt = bt & 511, bb = bt >> 9;
        xw[(size_t)(tt * 64 + bb) * NG + g] = (__bf16)(acc[mt][nt][r] + bv);
      }
    }
  }
}

// ---------------- persistent LSTM scan ----------------
// 256 blocks x 256 thr. block: ms=bid&3 -> batches [ms*16,+16); nj=bid>>2 -> j in [nj*16,+16)
// wave w K-splits [w*256,+256). U fragments REGISTER-RESIDENT.
//
// Sync protocol (tag-in-data): h = o*sig(c) >= 0 so the bf16 sign bit is free.
// Producer stores h_{t+1} with sign bit = (t+1)&1. Consumer polls buf[t%3]
// until EVERY element's sign bit == t&1. Stale occupant (h_{t-3}) has the
// opposite parity — can never look ready; partially-landed stores fail the
// per-element check (2B stores are atomic) and simply retry.
// Poll = NARROW probe spin (frag0, 1KB/wave) then ONE full 8-frag load with
// verify (R6 showed full-width spins blow +70MB HBM traffic).
// Overwrite safety (no end-of-step barrier): seeing h_t complete implies all
// group blocks are past step t-1, hence long past their step t-2 reads — so
// writing h_{t+1} over h_{t-2}'s slot is safe. zp is double-buffered by step
// parity (the one remaining __syncthreads separates zp write from reduce).
// xw/ids prefetched TWO steps ahead: the poll's vmcnt(0) then drains loads
// issued a full step-period earlier — xw HBM latency can never stall a poll.
__global__ __launch_bounds__(256, 1) void k_lstm(
    const int* __restrict__ ids, const __bf16* __restrict__ xw,
    const __bf16* __restrict__ Ut, float* __restrict__ out,
    __bf16* __restrict__ hb) {
  extern __shared__ char dynlds[];
  float* ost = (float*)dynlds;               // 32 KB: U staging window, then out stage [32][256]
  float* zp  = (float*)(dynlds + 32768);     // 2 x 32 KB: parity-double-buffered z partials

  const int tid = threadIdx.x;
  const int lane = tid & 63, w = tid >> 6;
  const int bid = blockIdx.x;
  const int ms = bid & 3, nj = bid >> 2;
  const int b0 = ms * 16, j0 = nj * 16;

  const int bn = lane & 15;  // n (j-local) for B frags / MFMA
  const int kc = lane >> 4;  // k-chunk 0..3

  // ---- stage U fragments through a 32KB window, chunk per gate q ----
  bf16x8 Bf[8][4];
#pragma unroll
  for (int q = 0; q < 4; ++q) {
#pragma unroll
    for (int ks = 0; ks < 8; ++ks) {
      const __bf16* src =
          Ut + (size_t)(q * NH + j0 + bn) * NH + w * 256 + ks * 32 + kc * 8;
      gl_lds16(src, (char*)dynlds + ((w * 8 + ks) << 10));
    }
    __syncthreads();
#pragma unroll
    for (int ks = 0; ks < 8; ++ks)
      Bf[ks][q] =
          *(const bf16x8*)((char*)dynlds + (((w * 8 + ks) << 6) + lane) * 16);
    __syncthreads();
  }

  const int eb = tid >> 4, ej = tid & 15;
  const int bg = b0 + eb, jg = j0 + ej;
  float c_st = 0.0f, h_st = 0.0f;

  const int am = lane & 15;  // batch row for A frags
  const unsigned long long hlane =
      (unsigned long long)(hb) + ((b0 + am) * NH + w * 256 + kc * 8) * 2ull;
  const unsigned long long hown =
      (unsigned long long)(hb) + (bg * NH + jg) * 2ull;

  unsigned offR = 0, offW = HBUF_STRIDE, offF = 2 * HBUF_STRIDE;

  // conflict-free zp read index: par(b) = ((b>>2)^b)&1 puts the 4 b's a wave
  // touches into both bank halves (2-way on both write and read = free)
  const int parE = ((eb >> 2) ^ eb) & 1;
  const int rbase = eb * 32 + (parE << 4) + ej;

  // pipeline prologue: xw/ids for t=0 (current) and t=1 (next)
  const __bf16* xwp0 = xw + ((size_t)(0 * 64 + bg) << 12) + jg;
  __bf16 xr0 = xwp0[0], xr1 = xwp0[NH], xr2 = xwp0[2 * NH], xr3 = xwp0[3 * NH];
  int idv = ids[bg * NT + 0];
  const __bf16* xwp1 = xw + ((size_t)(1 * 64 + bg) << 12) + jg;
  __bf16 nx0 = xwp1[0], nx1 = xwp1[NH], nx2 = xwp1[2 * NH], nx3 = xwp1[3 * NH];
  int nid = ids[bg * NT + 1];

#pragma unroll 1
  for (int t = 0; t < NT; ++t) {
    const unsigned long long hbR = hlane + offR;
    const unsigned expectTag = (t & 1) ? 0x80008000u : 0u;

    // A) cheap probe: spin on fragment 0 only until its tags match
    {
      bool ok;
      do {
        i32x4 v;
        asm volatile(
            "global_load_dwordx4 %0, %[a], off sc0 sc1\n\t"
            "s_waitcnt vmcnt(0)"
            : "=&v"(v) : [a] "v"(hbR) : "memory");
        unsigned b = (unsigned)((v[0] ^ (int)expectTag) | (v[1] ^ (int)expectTag) |
                                (v[2] ^ (int)expectTag) | (v[3] ^ (int)expectTag));
        ok = __all((int)((b & 0x80008000u) == 0));
      } while (!ok);
    }

    // B) full slice load + full tag verify (stores may land out of order)
    i32x4 Ar[8];
    for (;;) {
      load_h_frags(hbR, Ar);
      unsigned bad = 0;
#pragma unroll
      for (int i = 0; i < 8; ++i)
        bad |= (unsigned)((Ar[i][0] ^ (int)expectTag) | (Ar[i][1] ^ (int)expectTag) |
                          (Ar[i][2] ^ (int)expectTag) | (Ar[i][3] ^ (int)expectTag));
      if (__all((int)((bad & 0x80008000u) == 0))) break;
    }

    // C) prefetch xw/ids for t+2 — plain cached loads (cross-block LLC reuse).
    //    Drained by the poll at step t+1, a full step-period away: the xw
    //    HBM miss latency can never surface in a poll's vmcnt(0).
    const int tp = (t + 2) & (NT - 1);
    const __bf16* xwn = xw + ((size_t)(tp * 64 + bg) << 12) + jg;
    __bf16 mx0 = xwn[0], mx1 = xwn[NH], mx2 = xwn[2 * NH], mx3 = xwn[3 * NH];
    int mid_ = ids[bg * NT + tp];

    // D) strip generation tags (sign bits) — only odd steps carry them
    if (t & 1) {
#pragma unroll
      for (int i = 0; i < 8; ++i) {
        Ar[i][0] &= 0x7FFF7FFF; Ar[i][1] &= 0x7FFF7FFF;
        Ar[i][2] &= 0x7FFF7FFF; Ar[i][3] &= 0x7FFF7FFF;
      }
    }

    // E) MFMA: z partials, B-fragments from registers
    f32x4 acc[4] = {{0, 0, 0, 0}, {0, 0, 0, 0}, {0, 0, 0, 0}, {0, 0, 0, 0}};
#pragma unroll
    for (int ks = 0; ks < 8; ++ks) {
      bf16x8 a = __builtin_bit_cast(bf16x8, Ar[ks]);
#pragma unroll
      for (int q = 0; q < 4; ++q)
        acc[q] = __builtin_amdgcn_mfma_f32_16x16x32_bf16(a, Bf[ks][q], acc[q], 0, 0, 0);
    }

    // F) partials to parity LDS buffer, conflict-free: b = kc*4+r, par = (kc^r)&1
    float* zpp = zp + ((t & 1) << 13);
#pragma unroll
    for (int q = 0; q < 4; ++q)
#pragma unroll
      for (int r = 0; r < 4; ++r)
        zpp[((w * 4 + q) << 9) + ((kc * 4 + r) << 5) + (((kc ^ r) & 1) << 4) + bn] =
            acc[q][r];
    __syncthreads();  // BLOCK GATE: all 4 waves' polls passed + zp complete

    // G) reduce + gates
    float z0 = 0, z1 = 0, z2 = 0, z3 = 0;
#pragma unroll
    for (int wv = 0; wv < 4; ++wv) {
      z0 += zpp[((wv * 4 + 0) << 9) + rbase];
      z1 += zpp[((wv * 4 + 1) << 9) + rbase];
      z2 += zpp[((wv * 4 + 2) << 9) + rbase];
      z3 += zpp[((wv * 4 + 3) << 9) + rbase];
    }
    z0 += (float)xr0; z1 += (float)xr1; z2 += (float)xr2; z3 += (float)xr3;
    float iv = sigf(z0), fv = sigf(z1), gv = sigf(z2), ov = sigf(z3);
    float cn = fv * c_st + iv * gv;
    float hn = ov * sigf(cn);
    bool m = (idv != 0);
    c_st = m ? cn : c_st;
    h_st = m ? hn : h_st;

    // H) release h_{t+1} immediately — tagged with (t+1)&1 in the sign bit.
    {
      unsigned hv = (unsigned)__builtin_bit_cast(unsigned short, (__bf16)h_st) |
                    ((unsigned)((t + 1) & 1) << 15);
      unsigned long long ha = hown + offW;
      asm volatile(
          "global_store_short %[a], %[d], off sc0 sc1"
          :: [a] "v"(ha), [d] "v"(hv) : "memory");
    }

    // I) stage out in LDS (thread-private slots — no barrier needed);
    //    dump every 32 steps (non-temporal, off the serial path)
    ost[(t & 31) * 256 + tid] = h_st;
    if ((t & 31) == 31) {
      float* ob = out + (size_t)bg * (NT * NH) + (size_t)(t - 31) * NH + jg;
#pragma unroll
      for (int s = 0; s < 32; ++s)
        __builtin_nontemporal_store(ost[s * 256 + tid], ob + (size_t)s * NH);
    }

    // J) rotate buffers + two-stage pipeline registers (no end-of-step
    //    barrier: zp parity double-buffer makes next step's writes safe)
    unsigned tmp = offR; offR = offW; offW = offF; offF = tmp;
    xr0 = nx0; xr1 = nx1; xr2 = nx2; xr3 = nx3; idv = nid;
    nx0 = mx0; nx1 = mx1; nx2 = mx2; nx3 = mx3; nid = mid_;
  }

  // final h, c
  out[33554432u + bg * NH + jg] = h_st;
  out[33554432u + 65536u + bg * NH + jg] = c_st;
}

// ---------------- launch ----------------
extern "C" void kernel_launch(void* const* d_in, const int* in_sizes, int n_in,
                              void* d_out, int out_size, void* d_ws, size_t ws_size,
                              hipStream_t stream) {
  const int* ids = (const int*)d_in[0];
  const float* E = (const float*)d_in[1];
  const float* W = (const float*)d_in[2];
  const float* U = (const float*)d_in[3];
  const float* bias = (const float*)d_in[4];
  char* ws = (char*)d_ws;
  __bf16* Ebf = (__bf16*)(ws + OFF_EB);
  __bf16* Wt = (__bf16*)(ws + OFF_WT);
  __bf16* Ut = (__bf16*)(ws + OFF_UT);
  __bf16* xw = (__bf16*)(ws + OFF_XW);
  __bf16* hb = (__bf16*)(ws + OFF_H);
  float* out = (float*)d_out;

  // allow 96 KB dynamic LDS for k_lstm (idempotent; safe under graph capture)
  (void)hipFuncSetAttribute((const void*)k_lstm,
                            hipFuncAttributeMaxDynamicSharedMemorySize, 98304);

  // buf0 = h_0 = zeros (tag 0 == ready for t=0); buf1 = zeros (sign clear ==
  // NOT ready for t=1, which expects tag 1)
  hipLaunchKernelGGL(k_zero, dim3(64), dim3(256), 0, stream, (uint4*)(ws + OFF_H), 16384);
  // E -> bf16
  hipLaunchKernelGGL(k_cvt, dim3(2048), dim3(256), 0, stream, E, Ebf, 4096000);
  // W^T, U^T -> bf16
  hipLaunchKernelGGL(k_transpose, dim3(64, 8), dim3(256), 0, stream, W, Wt, 512, 4096);
  hipLaunchKernelGGL(k_transpose, dim3(64, 16), dim3(256), 0, stream, U, Ut, 1024, 4096);
  // xw = gather(E)@W + b
  hipLaunchKernelGGL(k_gemm_xw, dim3(8192), dim3(256), 0, stream, ids, Ebf, Wt, bias, xw);
  // buf2: sign-set fill (NOT ready for t=2, which expects tag 0).
  // Aliases head of Ebf — must run AFTER the GEMM.
  hipLaunchKernelGGL(k_fill, dim3(32), dim3(256), 0, stream,
                     (uint4*)(ws + OFF_H + 2 * HBUF_STRIDE), 8192);
  // persistent LSTM scan
  hipLaunchKernelGGL(k_lstm, dim3(256), dim3(256), 98304, stream, ids, xw, Ut, out, hb);
}